// Round 4
// baseline (2786.576 us; speedup 1.0000x reference)
//
#include <hip/hip_runtime.h>
#include <math.h>

constexpr int N_NODES = 500000;
constexpr int N_EDGES = 16000000;
constexpr int BSHIFT  = 12;
constexpr int BSZ     = 1 << BSHIFT;                  // 4096 nodes per bucket
constexpr int NB      = (N_NODES + BSZ - 1) / BSZ;    // 123 buckets
constexpr int NT2     = NB * NB;                      // 15129 tiles
constexpr int CHK     = 16384;                        // slots per block
constexpr int NCHK    = (N_EDGES + CHK - 1) / CHK;    // 977 blocks

// ---------------------------------------------------------------------------
// FAST PATH: two-level bucket sort -> all edge aggregation happens in LDS.
//   s[k] = sum_v (dv*outco[v]+dv^2)*h[v,k] + N*b2[k]
//        = sum_e w*dis[d]*(dis[s]*h[s,k])  (k_out, edge-sum, no scatter)
//        + sum_v dv^2*h[v,k]               (k_h self term)
// ws layout (bytes):
//   [0)              A       : 16M uint2 (dst-bucket-sorted payload) 128 MB
//   [128,000,000)    deg     : N f32   \  memset1 (4 MB)
//   [130,000,000)    inagg   : N f32   /
//   [132,000,000)    y       : N f32
//   [134,000,000)    dis     : N f32
//   [136,000,000)    g2      : 2N f32 (dis*h interleaved)
//   [140,000,000)    meta    : counts_blkA[NB*NCHK] basesA[NB*NCHK]
//                              offsets1[NB+1] counts2[NT2] sacc[2]
//                              offsets2[NT2+1] cursor2[NT2]
// B (tile-sorted payload) reuses d_in[1] (edge_index, 128 MB) — inputs are
// fully consumed after k_scatter1, and the harness restores d_in before
// every launch.
// ---------------------------------------------------------------------------

// ---- pass 1: per-chunk dst-bucket histograms (deterministic bases) ----
__global__ __launch_bounds__(256) void k_count1(const int* __restrict__ dst,
                                                unsigned* __restrict__ counts_blkA) {
    __shared__ unsigned hist[NB];
    int c = blockIdx.x;
    for (int t = threadIdx.x; t < NB; t += 256) hist[t] = 0;
    __syncthreads();
    int lo = c * CHK, hi = min(lo + CHK, N_EDGES);
    for (int e = lo + threadIdx.x; e < hi; e += 256)
        atomicAdd(&hist[dst[e] >> BSHIFT], 1u);
    __syncthreads();
    for (int b = threadIdx.x; b < NB; b += 256)
        counts_blkA[b * NCHK + c] = hist[b];
}

__global__ __launch_bounds__(256) void k_scanA(const unsigned* __restrict__ counts,
                                               unsigned* __restrict__ bases,
                                               unsigned* __restrict__ offsets1) {
    __shared__ unsigned sums[256];
    const int NA = NB * NCHK;
    const int per = (NA + 255) / 256;
    int t = threadIdx.x;
    int s0 = t * per, s1 = min(s0 + per, NA);
    unsigned sum = 0;
    for (int i = s0; i < s1; ++i) sum += counts[i];
    sums[t] = sum;
    __syncthreads();
    if (t == 0) {
        unsigned run = 0;
        for (int i = 0; i < 256; ++i) { unsigned v = sums[i]; sums[i] = run; run += v; }
    }
    __syncthreads();
    unsigned run = sums[t];
    for (int i = s0; i < s1; ++i) {
        unsigned v = counts[i];
        bases[i] = run;
        if (i % NCHK == 0) offsets1[i / NCHK] = run;
        run += v;
    }
    if (t == 0) offsets1[NB] = (unsigned)N_EDGES;
}

// ---- pass 2: scatter into dst-bucket order; pack1 = (dst_local<<19)|src ----
__global__ __launch_bounds__(256) void k_scatter1(const int* __restrict__ src,
                                                  const int* __restrict__ dst,
                                                  const float* __restrict__ w,
                                                  const unsigned* __restrict__ bases,
                                                  uint2* __restrict__ A) {
    __shared__ unsigned sbase[NB];
    __shared__ unsigned lpos[NB];
    int c = blockIdx.x;
    for (int b = threadIdx.x; b < NB; b += 256) {
        sbase[b] = bases[b * NCHK + c];
        lpos[b] = 0;
    }
    __syncthreads();
    int lo = c * CHK, hi = min(lo + CHK, N_EDGES);
    for (int e = lo + threadIdx.x; e < hi; e += 256) {
        int d = dst[e];
        int b = d >> BSHIFT;
        unsigned p = sbase[b] + atomicAdd(&lpos[b], 1u);
        unsigned pack = ((unsigned)(d & (BSZ - 1)) << 19) | (unsigned)src[e];
        A[p] = make_uint2(pack, __float_as_uint(w[e]));
    }
}

// ---- pass 3: sub-bucket (src) histograms + deg via LDS bins ----
__global__ __launch_bounds__(256) void k_count2deg(const uint2* __restrict__ A,
                                                   const unsigned* __restrict__ offsets1,
                                                   unsigned* __restrict__ counts2,
                                                   float* __restrict__ deg) {
    __shared__ unsigned histj[NB];
    __shared__ float bins[BSZ];
    int c = blockIdx.x;
    int lo = c * CHK, hi = min(lo + CHK, N_EDGES);
    if (lo >= hi) return;
    int b = 0;
    while ((int)offsets1[b + 1] <= lo) ++b;
    while (lo < hi) {
        int segEnd = min(hi, (int)offsets1[b + 1]);
        for (int t = threadIdx.x; t < NB; t += 256) histj[t] = 0;
        for (int t = threadIdx.x; t < BSZ; t += 256) bins[t] = 0.0f;
        __syncthreads();
        for (int e = lo + threadIdx.x; e < segEnd; e += 256) {
            uint2 a = A[e];
            unsigned srcv = a.x & 0x7FFFFu;
            unsigned dl = a.x >> 19;
            atomicAdd(&histj[srcv >> BSHIFT], 1u);
            atomicAdd(&bins[dl], __uint_as_float(a.y));
        }
        __syncthreads();
        for (int t = threadIdx.x; t < NB; t += 256)
            if (histj[t]) atomicAdd(&counts2[b * NB + t], histj[t]);
        int nbase = b << BSHIFT;
        for (int t = threadIdx.x; t < BSZ; t += 256) {
            int node = nbase + t;
            if (node < N_NODES && bins[t] != 0.0f) unsafeAtomicAdd(&deg[node], bins[t]);
        }
        __syncthreads();
        lo = segEnd; ++b;
    }
}

__global__ __launch_bounds__(256) void k_scan2(const unsigned* __restrict__ counts2,
                                               unsigned* __restrict__ offsets2,
                                               unsigned* __restrict__ cursor2) {
    __shared__ unsigned sums[256];
    const int per = (NT2 + 255) / 256;
    int t = threadIdx.x;
    int s0 = t * per, s1 = min(s0 + per, NT2);
    unsigned sum = 0;
    for (int i = s0; i < s1; ++i) sum += counts2[i];
    sums[t] = sum;
    __syncthreads();
    if (t == 0) {
        unsigned run = 0;
        for (int i = 0; i < 256; ++i) { unsigned v = sums[i]; sums[i] = run; run += v; }
    }
    __syncthreads();
    unsigned run = sums[t];
    for (int i = s0; i < s1; ++i) {
        unsigned v = counts2[i];
        offsets2[i] = run;
        cursor2[i] = run;
        run += v;
    }
    if (t == 0) offsets2[NT2] = (unsigned)N_EDGES;
}

__global__ __launch_bounds__(256) void k_dis(const float* __restrict__ deg,
                                             const float* __restrict__ x,
                                             float* __restrict__ dis,
                                             float* __restrict__ y) {
    int i = blockIdx.x * blockDim.x + threadIdx.x;
    if (i < N_NODES) {
        float d = rsqrtf(1.0f + deg[i]);   // +1 = self-loop
        dis[i] = d;
        y[i] = d * x[i];
    }
}

// ---- pass 4: scatter into (dst-bucket, src-bucket) tile order ----
// pack2 = (src_local<<12) | dst_local  (24 bits)
__global__ __launch_bounds__(256) void k_scatter2(const uint2* __restrict__ A,
                                                  const unsigned* __restrict__ offsets1,
                                                  unsigned* __restrict__ cursor2,
                                                  uint2* __restrict__ B) {
    __shared__ unsigned histj[NB];
    __shared__ unsigned lbase[NB];
    int c = blockIdx.x;
    int lo = c * CHK, hi = min(lo + CHK, N_EDGES);
    if (lo >= hi) return;
    int b = 0;
    while ((int)offsets1[b + 1] <= lo) ++b;
    while (lo < hi) {
        int segEnd = min(hi, (int)offsets1[b + 1]);
        for (int t = threadIdx.x; t < NB; t += 256) histj[t] = 0;
        __syncthreads();
        for (int e = lo + threadIdx.x; e < segEnd; e += 256)
            atomicAdd(&histj[(A[e].x & 0x7FFFFu) >> BSHIFT], 1u);
        __syncthreads();
        for (int t = threadIdx.x; t < NB; t += 256) {
            unsigned h = histj[t];
            lbase[t] = h ? atomicAdd(&cursor2[b * NB + t], h) : 0u;
        }
        __syncthreads();
        for (int t = threadIdx.x; t < NB; t += 256) histj[t] = 0;  // reuse as lpos
        __syncthreads();
        for (int e = lo + threadIdx.x; e < segEnd; e += 256) {
            uint2 a = A[e];
            unsigned srcv = a.x & 0x7FFFFu;
            unsigned dl = a.x >> 19;
            unsigned j = srcv >> BSHIFT;
            unsigned p = lbase[j] + atomicAdd(&histj[j], 1u);
            B[p] = make_uint2(((srcv & (BSZ - 1)) << BSHIFT) | dl, a.y);
        }
        __syncthreads();
        lo = segEnd; ++b;
    }
}

// ---- layer-1 aggregation: inagg[d] += w*y[s], all LDS-local ----
__global__ __launch_bounds__(256) void k_in(const uint2* __restrict__ B,
                                            const unsigned* __restrict__ offsets2,
                                            const float* __restrict__ y,
                                            float* __restrict__ inagg) {
    __shared__ float bins[BSZ];
    __shared__ float yseg[BSZ];
    int c = blockIdx.x;
    int lo = c * CHK, hi = min(lo + CHK, N_EDGES);
    if (lo >= hi) return;
    int tl = 0, tr = NT2;
    while (tl + 1 < tr) { int m = (tl + tr) >> 1; if ((int)offsets2[m] <= lo) tl = m; else tr = m; }
    int t = tl, curb = -1, curj = -1;
    while (lo < hi) {
        while ((int)offsets2[t + 1] <= lo) ++t;
        int b = t / NB, j = t - b * NB;
        if (b != curb) {
            __syncthreads();
            if (curb >= 0) {
                int nbase = curb << BSHIFT;
                for (int i = threadIdx.x; i < BSZ; i += 256) {
                    int node = nbase + i;
                    if (node < N_NODES && bins[i] != 0.0f) unsafeAtomicAdd(&inagg[node], bins[i]);
                }
                __syncthreads();
            }
            for (int i = threadIdx.x; i < BSZ; i += 256) bins[i] = 0.0f;
            curb = b; curj = -1;
        }
        if (j != curj) {
            __syncthreads();
            int nbase = j << BSHIFT;
            for (int i = threadIdx.x; i < BSZ; i += 256) {
                int node = nbase + i;
                yseg[i] = (node < N_NODES) ? y[node] : 0.0f;
            }
            curj = j;
            __syncthreads();
        }
        int segEnd = min(hi, (int)offsets2[t + 1]);
        for (int e = lo + threadIdx.x; e < segEnd; e += 256) {
            uint2 a = B[e];
            unsigned sl = a.x >> BSHIFT;
            unsigned dl = a.x & (BSZ - 1);
            atomicAdd(&bins[dl], __uint_as_float(a.y) * yseg[sl]);
        }
        lo = segEnd;
    }
    __syncthreads();
    if (curb >= 0) {
        int nbase = curb << BSHIFT;
        for (int i = threadIdx.x; i < BSZ; i += 256) {
            int node = nbase + i;
            if (node < N_NODES && bins[i] != 0.0f) unsafeAtomicAdd(&inagg[node], bins[i]);
        }
    }
}

// ---- per-node MLP; g2 = dis*h; accumulate self-loop term dv^2*h ----
__global__ __launch_bounds__(256) void k_h(const float* __restrict__ dis,
                                           const float* __restrict__ x,
                                           const float* __restrict__ inagg,
                                           const float* __restrict__ W1,
                                           const float* __restrict__ b1,
                                           const float* __restrict__ W2,
                                           float* __restrict__ g2,
                                           float* __restrict__ sacc) {
    int i = blockIdx.x * blockDim.x + threadIdx.x;
    float c0 = 0.0f, c1 = 0.0f;
    if (i < N_NODES) {
        float dv = dis[i];
        float agg1 = dv * (inagg[i] + dv * x[i]);
        float h0 = 0.0f, h1 = 0.0f;
#pragma unroll
        for (int jj = 0; jj < 16; ++jj) {
            float a = fmaxf(fmaf(agg1, W1[jj], b1[jj]), 0.0f);
            h0 = fmaf(a, W2[2 * jj + 0], h0);
            h1 = fmaf(a, W2[2 * jj + 1], h1);
        }
        g2[2 * i + 0] = dv * h0;
        g2[2 * i + 1] = dv * h1;
        c0 = dv * dv * h0;
        c1 = dv * dv * h1;
    }
#pragma unroll
    for (int off = 32; off > 0; off >>= 1) {
        c0 += __shfl_down(c0, off, 64);
        c1 += __shfl_down(c1, off, 64);
    }
    __shared__ float red0[4], red1[4];
    int wave = threadIdx.x >> 6, lane = threadIdx.x & 63;
    if (lane == 0) { red0[wave] = c0; red1[wave] = c1; }
    __syncthreads();
    if (threadIdx.x == 0) {
        atomicAdd(&sacc[0], red0[0] + red0[1] + red0[2] + red0[3]);
        atomicAdd(&sacc[1], red1[0] + red1[1] + red1[2] + red1[3]);
    }
}

// ---- layer-2 out-contribution: sum_e w*dis[d]*g2[s], all LDS-local ----
__global__ __launch_bounds__(256) void k_out(const uint2* __restrict__ B,
                                             const unsigned* __restrict__ offsets2,
                                             const float* __restrict__ dis,
                                             const float* __restrict__ g2,
                                             float* __restrict__ sacc) {
    __shared__ float disL[BSZ];
    __shared__ float gL[2 * BSZ];
    __shared__ float red0[4], red1[4];
    int c = blockIdx.x;
    int lo = c * CHK, hi = min(lo + CHK, N_EDGES);
    float c0 = 0.0f, c1 = 0.0f;
    int tl = 0, tr = NT2;
    while (tl + 1 < tr) { int m = (tl + tr) >> 1; if ((int)offsets2[m] <= lo) tl = m; else tr = m; }
    int t = tl, curb = -1, curj = -1;
    while (lo < hi) {
        while ((int)offsets2[t + 1] <= lo) ++t;
        int b = t / NB, j = t - b * NB;
        if (b != curb) {
            __syncthreads();
            int nbase = b << BSHIFT;
            for (int i = threadIdx.x; i < BSZ; i += 256) {
                int node = nbase + i;
                disL[i] = (node < N_NODES) ? dis[node] : 0.0f;
            }
            curb = b;
            __syncthreads();
        }
        if (j != curj) {
            __syncthreads();
            int nbase2 = j << (BSHIFT + 1);
            for (int i = threadIdx.x; i < 2 * BSZ; i += 256) {
                int idx = nbase2 + i;
                gL[i] = (idx < 2 * N_NODES) ? g2[idx] : 0.0f;
            }
            curj = j;
            __syncthreads();
        }
        int segEnd = min(hi, (int)offsets2[t + 1]);
        for (int e = lo + threadIdx.x; e < segEnd; e += 256) {
            uint2 a = B[e];
            unsigned sl = a.x >> BSHIFT;
            unsigned dl = a.x & (BSZ - 1);
            float wd = __uint_as_float(a.y) * disL[dl];
            c0 = fmaf(wd, gL[2 * sl + 0], c0);
            c1 = fmaf(wd, gL[2 * sl + 1], c1);
        }
        lo = segEnd;
    }
#pragma unroll
    for (int off = 32; off > 0; off >>= 1) {
        c0 += __shfl_down(c0, off, 64);
        c1 += __shfl_down(c1, off, 64);
    }
    int wave = threadIdx.x >> 6, lane = threadIdx.x & 63;
    if (lane == 0) { red0[wave] = c0; red1[wave] = c1; }
    __syncthreads();
    if (threadIdx.x == 0) {
        atomicAdd(&sacc[0], red0[0] + red0[1] + red0[2] + red0[3]);
        atomicAdd(&sacc[1], red1[0] + red1[1] + red1[2] + red1[3]);
    }
}

__global__ void k_final(const float* __restrict__ sacc,
                        const float* __restrict__ b2,
                        float* __restrict__ out) {
    if (threadIdx.x == 0 && blockIdx.x == 0) {
        float s0 = sacc[0] + (float)N_NODES * b2[0];
        float s1 = sacc[1] + (float)N_NODES * b2[1];
        float m = fmaxf(s0, s1);
        float e0 = __expf(s0 - m);
        float e1 = __expf(s1 - m);
        float inv = 1.0f / (e0 + e1);
        out[0] = e0 * inv;
        out[1] = e1 * inv;
    }
}

// ---------------- fallback path (R1 structure, ~8 MB ws) ----------------

__global__ __launch_bounds__(256) void k_init_fb(float* __restrict__ deg,
                                                 float* __restrict__ inagg,
                                                 float* __restrict__ outco,
                                                 float* __restrict__ sacc) {
    int i = blockIdx.x * blockDim.x + threadIdx.x;
    if (i < N_NODES) { deg[i] = 1.0f; inagg[i] = 0.0f; outco[i] = 0.0f; }
    if (i < 2) sacc[i] = 0.0f;
}

__global__ __launch_bounds__(256) void k_deg_fb(const int4* __restrict__ dst4,
                                                const float4* __restrict__ w4,
                                                float* __restrict__ deg) {
    int i = blockIdx.x * blockDim.x + threadIdx.x;
    int4 d = dst4[i]; float4 w = w4[i];
    atomicAdd(&deg[d.x], w.x); atomicAdd(&deg[d.y], w.y);
    atomicAdd(&deg[d.z], w.z); atomicAdd(&deg[d.w], w.w);
}

__global__ __launch_bounds__(256) void k_dis_fb(float* __restrict__ degdis,
                                                const float* __restrict__ x,
                                                float* __restrict__ y) {
    int i = blockIdx.x * blockDim.x + threadIdx.x;
    if (i < N_NODES) { float d = rsqrtf(degdis[i]); degdis[i] = d; y[i] = d * x[i]; }
}

__global__ __launch_bounds__(256) void k_edge2_fb(const int4* __restrict__ src4,
                                                  const int4* __restrict__ dst4,
                                                  const float4* __restrict__ w4,
                                                  const float* __restrict__ dis,
                                                  const float* __restrict__ y,
                                                  float* __restrict__ inagg,
                                                  float* __restrict__ outco) {
    int i = blockIdx.x * blockDim.x + threadIdx.x;
    int4 s = src4[i]; int4 d = dst4[i]; float4 w = w4[i];
    atomicAdd(&inagg[d.x], w.x * y[s.x]); atomicAdd(&inagg[d.y], w.y * y[s.y]);
    atomicAdd(&inagg[d.z], w.z * y[s.z]); atomicAdd(&inagg[d.w], w.w * y[s.w]);
    atomicAdd(&outco[s.x], w.x * dis[d.x]); atomicAdd(&outco[s.y], w.y * dis[d.y]);
    atomicAdd(&outco[s.z], w.z * dis[d.z]); atomicAdd(&outco[s.w], w.w * dis[d.w]);
}

__global__ __launch_bounds__(256) void k_node_fb(const float* __restrict__ dis,
                                                 const float* __restrict__ x,
                                                 const float* __restrict__ inagg,
                                                 const float* __restrict__ outco,
                                                 const float* __restrict__ W1,
                                                 const float* __restrict__ b1,
                                                 const float* __restrict__ W2,
                                                 float* __restrict__ sacc) {
    int i = blockIdx.x * blockDim.x + threadIdx.x;
    float c0 = 0.0f, c1 = 0.0f;
    if (i < N_NODES) {
        float dv = dis[i];
        float agg1 = dv * (inagg[i] + dv * x[i]);
        float coef = dv * outco[i] + dv * dv;
        float h0 = 0.0f, h1 = 0.0f;
#pragma unroll
        for (int j = 0; j < 16; ++j) {
            float a = fmaxf(fmaf(agg1, W1[j], b1[j]), 0.0f);
            h0 = fmaf(a, W2[2 * j + 0], h0);
            h1 = fmaf(a, W2[2 * j + 1], h1);
        }
        c0 = coef * h0; c1 = coef * h1;
    }
#pragma unroll
    for (int off = 32; off > 0; off >>= 1) {
        c0 += __shfl_down(c0, off, 64);
        c1 += __shfl_down(c1, off, 64);
    }
    __shared__ float red0[4], red1[4];
    int wave = threadIdx.x >> 6, lane = threadIdx.x & 63;
    if (lane == 0) { red0[wave] = c0; red1[wave] = c1; }
    __syncthreads();
    if (threadIdx.x == 0) {
        atomicAdd(&sacc[0], red0[0] + red0[1] + red0[2] + red0[3]);
        atomicAdd(&sacc[1], red1[0] + red1[1] + red1[2] + red1[3]);
    }
}

extern "C" void kernel_launch(void* const* d_in, const int* in_sizes, int n_in,
                              void* d_out, int out_size, void* d_ws, size_t ws_size,
                              hipStream_t stream) {
    const float* x  = (const float*)d_in[0];
    int*         ei = (int*)d_in[1];            // [2,E] int32 (row0 src, row1 dst)
    const float* ew = (const float*)d_in[2];
    const float* W1 = (const float*)d_in[3];
    const float* b1 = (const float*)d_in[4];
    const float* W2 = (const float*)d_in[5];
    const float* b2 = (const float*)d_in[6];
    float* out = (float*)d_out;

    const int* src = ei;
    const int* dst = ei + N_EDGES;

    const int TB = 256;
    const int nodeBlocks = (N_NODES + TB - 1) / TB;

    // fast-path layout
    char* base = (char*)d_ws;
    uint2*    A          = (uint2*)base;
    float*    deg        = (float*)(base + 128000000);
    float*    inagg      = (float*)(base + 130000000);
    float*    y          = (float*)(base + 132000000);
    float*    dis        = (float*)(base + 134000000);
    float*    g2         = (float*)(base + 136000000);
    unsigned* meta       = (unsigned*)(base + 140000000);
    unsigned* counts_blkA = meta;
    unsigned* basesA      = counts_blkA + (size_t)NB * NCHK;
    unsigned* offsets1    = basesA + (size_t)NB * NCHK;
    unsigned* counts2     = offsets1 + (NB + 1);
    float*    sacc        = (float*)(counts2 + NT2);
    unsigned* offsets2    = (unsigned*)(sacc + 2);
    unsigned* cursor2     = offsets2 + (NT2 + 1);
    const size_t fastNeed = (size_t)(cursor2 + NT2 - (unsigned*)base) * 4 + 64;

    if (ws_size >= fastNeed) {
        uint2* B = (uint2*)ei;   // reuse edge_index buffer after it's consumed

        hipMemsetAsync(deg, 0, 4000000, stream);                       // deg+inagg
        hipMemsetAsync(counts2, 0, (size_t)(NT2 + 2) * 4, stream);     // counts2+sacc

        k_count1<<<NCHK, TB, 0, stream>>>(dst, counts_blkA);
        k_scanA<<<1, TB, 0, stream>>>(counts_blkA, basesA, offsets1);
        k_scatter1<<<NCHK, TB, 0, stream>>>(src, dst, ew, basesA, A);
        k_count2deg<<<NCHK, TB, 0, stream>>>(A, offsets1, counts2, deg);
        k_scan2<<<1, TB, 0, stream>>>(counts2, offsets2, cursor2);
        k_dis<<<nodeBlocks, TB, 0, stream>>>(deg, x, dis, y);
        k_scatter2<<<NCHK, TB, 0, stream>>>(A, offsets1, cursor2, B);
        k_in<<<NCHK, TB, 0, stream>>>(B, offsets2, y, inagg);
        k_h<<<nodeBlocks, TB, 0, stream>>>(dis, x, inagg, W1, b1, W2, g2, sacc);
        k_out<<<NCHK, TB, 0, stream>>>(B, offsets2, dis, g2, sacc);
        k_final<<<1, 64, 0, stream>>>(sacc, b2, out);
    } else {
        float* ws     = (float*)d_ws;
        float* degdis = ws;
        float* yf     = ws + N_NODES;
        float* inaggf = ws + 2 * N_NODES;
        float* outcof = ws + 3 * N_NODES;
        float* saccf  = ws + 4 * N_NODES;
        const int edgeBlocks = (N_EDGES / 4) / TB;

        k_init_fb<<<nodeBlocks, TB, 0, stream>>>(degdis, inaggf, outcof, saccf);
        k_deg_fb<<<edgeBlocks, TB, 0, stream>>>((const int4*)dst, (const float4*)ew, degdis);
        k_dis_fb<<<nodeBlocks, TB, 0, stream>>>(degdis, x, yf);
        k_edge2_fb<<<edgeBlocks, TB, 0, stream>>>((const int4*)src, (const int4*)dst,
                                                  (const float4*)ew, degdis, yf, inaggf, outcof);
        k_node_fb<<<nodeBlocks, TB, 0, stream>>>(degdis, x, inaggf, outcof, W1, b1, W2, saccf);
        k_final<<<1, 64, 0, stream>>>(saccf, b2, out);
    }
}

// Round 5
// 1005.703 us; speedup vs baseline: 2.7708x; 2.7708x over previous
//
#include <hip/hip_runtime.h>
#include <math.h>

constexpr int N_NODES   = 500000;
constexpr int N_EDGES   = 16000000;
constexpr int BSHIFT    = 12;
constexpr int BSZ       = 1 << BSHIFT;                 // 4096 nodes / bucket
constexpr int NB        = (N_NODES + BSZ - 1) / BSZ;   // 123 buckets
constexpr int CHK       = 16384;
constexpr int NCHK      = (N_EDGES + CHK - 1) / CHK;   // 977 chunks
constexpr int SPB_SHIFT = 4;
constexpr int SPB       = 1 << SPB_SHIFT;              // 16 slices / bucket

// ---------------------------------------------------------------------------
// v5: one-level dst-bucket sort; scatters become LDS-binned + coalesced
// staging writes (NO global atomics on the hot path); layer-2 "outco" is a
// pure edge reduction (no scatter at all).
//   s[k] = sum_e w*dis[d]*g2[s,k] + sum_v dv^2*h[v,k] + N*b2[k]
// ws layout (bytes):
//   [0)            A   : 16M uint2, dst-bucket-sorted, pack=(dst_local<<19)|src
//   [128,000,000)  y   : N f32
//   [130,000,000)  dis : N f32
//   [132,000,000)  g2  : N float2 (dis*hW2)
//   [136,000,000)  meta: counts_blkA[NB*NCHK] basesA[NB*NCHK] offsets1[NB+1]
//                        sacc[2]
// staging (NB*SPB*BSZ f32 = 32.2 MB) reuses d_in[1] (edge_index, 128 MB):
// src/dst fully consumed after k_scatter1; harness restores d_in every call.
// ---------------------------------------------------------------------------

__global__ __launch_bounds__(256) void k_count1(const int* __restrict__ dst,
                                                unsigned* __restrict__ counts_blkA) {
    __shared__ unsigned hist[NB];
    int c = blockIdx.x;
    for (int t = threadIdx.x; t < NB; t += 256) hist[t] = 0;
    __syncthreads();
    int lo = c * CHK, hi = min(lo + CHK, N_EDGES);
    for (int e = lo + threadIdx.x; e < hi; e += 256)
        atomicAdd(&hist[dst[e] >> BSHIFT], 1u);
    __syncthreads();
    for (int b = threadIdx.x; b < NB; b += 256)
        counts_blkA[b * NCHK + c] = hist[b];
}

__global__ __launch_bounds__(256) void k_scanA(const unsigned* __restrict__ counts,
                                               unsigned* __restrict__ bases,
                                               unsigned* __restrict__ offsets1) {
    __shared__ unsigned sums[256];
    const int NA = NB * NCHK;
    const int per = (NA + 255) / 256;
    int t = threadIdx.x;
    int s0 = t * per, s1 = min(s0 + per, NA);
    unsigned sum = 0;
    for (int i = s0; i < s1; ++i) sum += counts[i];
    sums[t] = sum;
    __syncthreads();
    if (t == 0) {
        unsigned run = 0;
        for (int i = 0; i < 256; ++i) { unsigned v = sums[i]; sums[i] = run; run += v; }
    }
    __syncthreads();
    unsigned run = sums[t];
    for (int i = s0; i < s1; ++i) {
        unsigned v = counts[i];
        bases[i] = run;
        if (i % NCHK == 0) offsets1[i / NCHK] = run;
        run += v;
    }
    if (t == 0) offsets1[NB] = (unsigned)N_EDGES;
}

__global__ __launch_bounds__(256) void k_scatter1(const int* __restrict__ src,
                                                  const int* __restrict__ dst,
                                                  const float* __restrict__ w,
                                                  const unsigned* __restrict__ bases,
                                                  uint2* __restrict__ A) {
    __shared__ unsigned sbase[NB];
    __shared__ unsigned lpos[NB];
    int c = blockIdx.x;
    for (int b = threadIdx.x; b < NB; b += 256) {
        sbase[b] = bases[b * NCHK + c];
        lpos[b] = 0;
    }
    __syncthreads();
    int lo = c * CHK, hi = min(lo + CHK, N_EDGES);
    for (int e = lo + threadIdx.x; e < hi; e += 256) {
        int d = dst[e];
        int b = d >> BSHIFT;
        unsigned p = sbase[b] + atomicAdd(&lpos[b], 1u);
        A[p] = make_uint2(((unsigned)(d & (BSZ - 1)) << 19) | (unsigned)src[e],
                          __float_as_uint(w[e]));
    }
}

// slice [e0,e1) of bucket b for this block
__device__ __forceinline__ void slice_bounds(const unsigned* offsets1,
                                             int& b, int& e0, int& e1) {
    b = blockIdx.x >> SPB_SHIFT;
    int s = blockIdx.x & (SPB - 1);
    int base = (int)offsets1[b];
    int len  = (int)offsets1[b + 1] - base;
    e0 = base + (int)(((long long)len * s) >> SPB_SHIFT);
    e1 = base + (int)(((long long)len * (s + 1)) >> SPB_SHIFT);
}

// deg[dl] += w  (LDS bins, coalesced flush to per-block staging slot)
__global__ __launch_bounds__(256) void k_deg(const uint2* __restrict__ A,
                                             const unsigned* __restrict__ offsets1,
                                             float* __restrict__ staging) {
    __shared__ float bins[BSZ];
    for (int i = threadIdx.x; i < BSZ; i += 256) bins[i] = 0.0f;
    int b, e0, e1;
    slice_bounds(offsets1, b, e0, e1);
    __syncthreads();
    for (int e = e0 + threadIdx.x; e < e1; e += 256) {
        uint2 a = A[e];
        atomicAdd(&bins[a.x >> 19], __uint_as_float(a.y));
    }
    __syncthreads();
    float* out = staging + (size_t)blockIdx.x * BSZ;
    for (int i = threadIdx.x; i < BSZ; i += 256) out[i] = bins[i];
}

// fold deg staging -> dis, y
__global__ __launch_bounds__(256) void k_dis(const float* __restrict__ staging,
                                             const float* __restrict__ x,
                                             float* __restrict__ dis,
                                             float* __restrict__ y) {
    int i = blockIdx.x * 256 + threadIdx.x;
    if (i >= N_NODES) return;
    int b = i >> BSHIFT, dl = i & (BSZ - 1);
    const float* st = staging + ((size_t)b << (BSHIFT + SPB_SHIFT)) + dl;
    float deg = 1.0f;  // self-loop
#pragma unroll
    for (int s = 0; s < SPB; ++s) deg += st[(size_t)s << BSHIFT];
    float d = rsqrtf(deg);
    dis[i] = d;
    y[i]   = d * x[i];
}

// inagg[dl] += w * y[src]  (random L2 gather on y; LDS bins; coalesced flush)
__global__ __launch_bounds__(256) void k_in(const uint2* __restrict__ A,
                                            const unsigned* __restrict__ offsets1,
                                            const float* __restrict__ y,
                                            float* __restrict__ staging) {
    __shared__ float bins[BSZ];
    for (int i = threadIdx.x; i < BSZ; i += 256) bins[i] = 0.0f;
    int b, e0, e1;
    slice_bounds(offsets1, b, e0, e1);
    __syncthreads();
    for (int e = e0 + threadIdx.x; e < e1; e += 256) {
        uint2 a = A[e];
        float yv = y[a.x & 0x7FFFFu];
        atomicAdd(&bins[a.x >> 19], __uint_as_float(a.y) * yv);
    }
    __syncthreads();
    float* out = staging + (size_t)blockIdx.x * BSZ;
    for (int i = threadIdx.x; i < BSZ; i += 256) out[i] = bins[i];
}

// fold inagg staging; per-node MLP; g2 = dis*hW2; self-loop term -> sacc
__global__ __launch_bounds__(256) void k_h(const float* __restrict__ staging,
                                           const float* __restrict__ dis,
                                           const float* __restrict__ x,
                                           const float* __restrict__ W1,
                                           const float* __restrict__ b1,
                                           const float* __restrict__ W2,
                                           float2* __restrict__ g2,
                                           float* __restrict__ sacc) {
    int i = blockIdx.x * 256 + threadIdx.x;
    float c0 = 0.0f, c1 = 0.0f;
    if (i < N_NODES) {
        int b = i >> BSHIFT, dl = i & (BSZ - 1);
        const float* st = staging + ((size_t)b << (BSHIFT + SPB_SHIFT)) + dl;
        float inagg = 0.0f;
#pragma unroll
        for (int s = 0; s < SPB; ++s) inagg += st[(size_t)s << BSHIFT];
        float dv   = dis[i];
        float agg1 = dv * (inagg + dv * x[i]);
        float h0 = 0.0f, h1 = 0.0f;
#pragma unroll
        for (int j = 0; j < 16; ++j) {
            float a = fmaxf(fmaf(agg1, W1[j], b1[j]), 0.0f);
            h0 = fmaf(a, W2[2 * j + 0], h0);
            h1 = fmaf(a, W2[2 * j + 1], h1);
        }
        g2[i] = make_float2(dv * h0, dv * h1);
        c0 = dv * dv * h0;
        c1 = dv * dv * h1;
    }
#pragma unroll
    for (int off = 32; off > 0; off >>= 1) {
        c0 += __shfl_down(c0, off, 64);
        c1 += __shfl_down(c1, off, 64);
    }
    __shared__ float red0[4], red1[4];
    int wave = threadIdx.x >> 6, lane = threadIdx.x & 63;
    if (lane == 0) { red0[wave] = c0; red1[wave] = c1; }
    __syncthreads();
    if (threadIdx.x == 0) {
        atomicAdd(&sacc[0], red0[0] + red0[1] + red0[2] + red0[3]);
        atomicAdd(&sacc[1], red1[0] + red1[1] + red1[2] + red1[3]);
    }
}

// pure edge reduction: sum_e w * dis[dst] * g2[src]  (dis LDS-local)
__global__ __launch_bounds__(256) void k_out(const uint2* __restrict__ A,
                                             const unsigned* __restrict__ offsets1,
                                             const float* __restrict__ dis,
                                             const float2* __restrict__ g2,
                                             float* __restrict__ sacc) {
    __shared__ float disL[BSZ];
    int b, e0, e1;
    slice_bounds(offsets1, b, e0, e1);
    int nbase = b << BSHIFT;
    for (int i = threadIdx.x; i < BSZ; i += 256) {
        int node = nbase + i;
        disL[i] = (node < N_NODES) ? dis[node] : 0.0f;
    }
    __syncthreads();
    float c0 = 0.0f, c1 = 0.0f;
    for (int e = e0 + threadIdx.x; e < e1; e += 256) {
        uint2 a = A[e];
        float2 g = g2[a.x & 0x7FFFFu];
        float wd = __uint_as_float(a.y) * disL[a.x >> 19];
        c0 = fmaf(wd, g.x, c0);
        c1 = fmaf(wd, g.y, c1);
    }
#pragma unroll
    for (int off = 32; off > 0; off >>= 1) {
        c0 += __shfl_down(c0, off, 64);
        c1 += __shfl_down(c1, off, 64);
    }
    __shared__ float red0[4], red1[4];
    int wave = threadIdx.x >> 6, lane = threadIdx.x & 63;
    if (lane == 0) { red0[wave] = c0; red1[wave] = c1; }
    __syncthreads();
    if (threadIdx.x == 0) {
        atomicAdd(&sacc[0], red0[0] + red0[1] + red0[2] + red0[3]);
        atomicAdd(&sacc[1], red1[0] + red1[1] + red1[2] + red1[3]);
    }
}

__global__ void k_final(const float* __restrict__ sacc,
                        const float* __restrict__ b2,
                        float* __restrict__ out) {
    if (threadIdx.x == 0 && blockIdx.x == 0) {
        float s0 = sacc[0] + (float)N_NODES * b2[0];
        float s1 = sacc[1] + (float)N_NODES * b2[1];
        float m = fmaxf(s0, s1);
        float e0 = __expf(s0 - m);
        float e1 = __expf(s1 - m);
        float inv = 1.0f / (e0 + e1);
        out[0] = e0 * inv;
        out[1] = e1 * inv;
    }
}

// ---------------- fallback path (R1 structure, ~8 MB ws) ----------------

__global__ __launch_bounds__(256) void k_init_fb(float* __restrict__ deg,
                                                 float* __restrict__ inagg,
                                                 float* __restrict__ outco,
                                                 float* __restrict__ sacc) {
    int i = blockIdx.x * blockDim.x + threadIdx.x;
    if (i < N_NODES) { deg[i] = 1.0f; inagg[i] = 0.0f; outco[i] = 0.0f; }
    if (i < 2) sacc[i] = 0.0f;
}

__global__ __launch_bounds__(256) void k_deg_fb(const int4* __restrict__ dst4,
                                                const float4* __restrict__ w4,
                                                float* __restrict__ deg) {
    int i = blockIdx.x * blockDim.x + threadIdx.x;
    int4 d = dst4[i]; float4 w = w4[i];
    atomicAdd(&deg[d.x], w.x); atomicAdd(&deg[d.y], w.y);
    atomicAdd(&deg[d.z], w.z); atomicAdd(&deg[d.w], w.w);
}

__global__ __launch_bounds__(256) void k_dis_fb(float* __restrict__ degdis,
                                                const float* __restrict__ x,
                                                float* __restrict__ y) {
    int i = blockIdx.x * blockDim.x + threadIdx.x;
    if (i < N_NODES) { float d = rsqrtf(degdis[i]); degdis[i] = d; y[i] = d * x[i]; }
}

__global__ __launch_bounds__(256) void k_edge2_fb(const int4* __restrict__ src4,
                                                  const int4* __restrict__ dst4,
                                                  const float4* __restrict__ w4,
                                                  const float* __restrict__ dis,
                                                  const float* __restrict__ y,
                                                  float* __restrict__ inagg,
                                                  float* __restrict__ outco) {
    int i = blockIdx.x * blockDim.x + threadIdx.x;
    int4 s = src4[i]; int4 d = dst4[i]; float4 w = w4[i];
    atomicAdd(&inagg[d.x], w.x * y[s.x]); atomicAdd(&inagg[d.y], w.y * y[s.y]);
    atomicAdd(&inagg[d.z], w.z * y[s.z]); atomicAdd(&inagg[d.w], w.w * y[s.w]);
    atomicAdd(&outco[s.x], w.x * dis[d.x]); atomicAdd(&outco[s.y], w.y * dis[d.y]);
    atomicAdd(&outco[s.z], w.z * dis[d.z]); atomicAdd(&outco[s.w], w.w * dis[d.w]);
}

__global__ __launch_bounds__(256) void k_node_fb(const float* __restrict__ dis,
                                                 const float* __restrict__ x,
                                                 const float* __restrict__ inagg,
                                                 const float* __restrict__ outco,
                                                 const float* __restrict__ W1,
                                                 const float* __restrict__ b1,
                                                 const float* __restrict__ W2,
                                                 float* __restrict__ sacc) {
    int i = blockIdx.x * blockDim.x + threadIdx.x;
    float c0 = 0.0f, c1 = 0.0f;
    if (i < N_NODES) {
        float dv = dis[i];
        float agg1 = dv * (inagg[i] + dv * x[i]);
        float coef = dv * outco[i] + dv * dv;
        float h0 = 0.0f, h1 = 0.0f;
#pragma unroll
        for (int j = 0; j < 16; ++j) {
            float a = fmaxf(fmaf(agg1, W1[j], b1[j]), 0.0f);
            h0 = fmaf(a, W2[2 * j + 0], h0);
            h1 = fmaf(a, W2[2 * j + 1], h1);
        }
        c0 = coef * h0; c1 = coef * h1;
    }
#pragma unroll
    for (int off = 32; off > 0; off >>= 1) {
        c0 += __shfl_down(c0, off, 64);
        c1 += __shfl_down(c1, off, 64);
    }
    __shared__ float red0[4], red1[4];
    int wave = threadIdx.x >> 6, lane = threadIdx.x & 63;
    if (lane == 0) { red0[wave] = c0; red1[wave] = c1; }
    __syncthreads();
    if (threadIdx.x == 0) {
        atomicAdd(&sacc[0], red0[0] + red0[1] + red0[2] + red0[3]);
        atomicAdd(&sacc[1], red1[0] + red1[1] + red1[2] + red1[3]);
    }
}

extern "C" void kernel_launch(void* const* d_in, const int* in_sizes, int n_in,
                              void* d_out, int out_size, void* d_ws, size_t ws_size,
                              hipStream_t stream) {
    const float* x  = (const float*)d_in[0];
    int*         ei = (int*)d_in[1];            // [2,E] int32 (row0 src, row1 dst)
    const float* ew = (const float*)d_in[2];
    const float* W1 = (const float*)d_in[3];
    const float* b1 = (const float*)d_in[4];
    const float* W2 = (const float*)d_in[5];
    const float* b2 = (const float*)d_in[6];
    float* out = (float*)d_out;

    const int* src = ei;
    const int* dst = ei + N_EDGES;

    const int TB = 256;
    const int nodeBlocks = (N_NODES + TB - 1) / TB;

    // fast-path layout in ws
    char* base = (char*)d_ws;
    uint2*    A   = (uint2*)base;
    float*    y   = (float*)(base + 128000000);
    float*    dis = (float*)(base + 130000000);
    float2*   g2  = (float2*)(base + 132000000);
    unsigned* counts_blkA = (unsigned*)(base + 136000000);
    unsigned* basesA      = counts_blkA + (size_t)NB * NCHK;
    unsigned* offsets1    = basesA + (size_t)NB * NCHK;
    float*    sacc        = (float*)(offsets1 + (NB + 1));
    const size_t fastNeed = (size_t)((char*)(sacc + 2) - base) + 64;

    if (ws_size >= fastNeed) {
        // staging reuses edge_index buffer (consumed after k_scatter1)
        float* staging = (float*)ei;   // NB*SPB*BSZ*4 = 32.2 MB <= 128 MB

        hipMemsetAsync(sacc, 0, 2 * sizeof(float), stream);

        k_count1<<<NCHK, TB, 0, stream>>>(dst, counts_blkA);
        k_scanA<<<1, TB, 0, stream>>>(counts_blkA, basesA, offsets1);
        k_scatter1<<<NCHK, TB, 0, stream>>>(src, dst, ew, basesA, A);
        k_deg<<<NB * SPB, TB, 0, stream>>>(A, offsets1, staging);
        k_dis<<<nodeBlocks, TB, 0, stream>>>(staging, x, dis, y);
        k_in<<<NB * SPB, TB, 0, stream>>>(A, offsets1, y, staging);
        k_h<<<nodeBlocks, TB, 0, stream>>>(staging, dis, x, W1, b1, W2, g2, sacc);
        k_out<<<NB * SPB, TB, 0, stream>>>(A, offsets1, dis, g2, sacc);
        k_final<<<1, 64, 0, stream>>>(sacc, b2, out);
    } else {
        float* ws     = (float*)d_ws;
        float* degdis = ws;
        float* yf     = ws + N_NODES;
        float* inaggf = ws + 2 * N_NODES;
        float* outcof = ws + 3 * N_NODES;
        float* saccf  = ws + 4 * N_NODES;
        const int edgeBlocks = (N_EDGES / 4) / TB;

        k_init_fb<<<nodeBlocks, TB, 0, stream>>>(degdis, inaggf, outcof, saccf);
        k_deg_fb<<<edgeBlocks, TB, 0, stream>>>((const int4*)dst, (const float4*)ew, degdis);
        k_dis_fb<<<nodeBlocks, TB, 0, stream>>>(degdis, x, yf);
        k_edge2_fb<<<edgeBlocks, TB, 0, stream>>>((const int4*)src, (const int4*)dst,
                                                  (const float4*)ew, degdis, yf, inaggf, outcof);
        k_node_fb<<<nodeBlocks, TB, 0, stream>>>(degdis, x, inaggf, outcof, W1, b1, W2, saccf);
        k_final<<<1, 64, 0, stream>>>(saccf, b2, out);
    }
}

// Round 6
// 795.181 us; speedup vs baseline: 3.5043x; 1.2647x over previous
//
#include <hip/hip_runtime.h>
#include <math.h>

constexpr int N_NODES   = 500000;
constexpr int N_EDGES   = 16000000;
constexpr int BSHIFT    = 12;
constexpr int BSZ       = 1 << BSHIFT;                 // 4096 nodes / bucket
constexpr int NB        = (N_NODES + BSZ - 1) / BSZ;   // 123 buckets
constexpr int CHK       = 6144;                        // edges per sort chunk (48 KB LDS)
constexpr int NCHK      = (N_EDGES + CHK - 1) / CHK;   // 2605 chunks
constexpr int SPB_SHIFT = 4;
constexpr int SPB       = 1 << SPB_SHIFT;              // 16 consumer slices / bucket

// ---------------------------------------------------------------------------
// v6: one-level dst-bucket sort with LDS chunk-sorted scatter (full-line
// writes; fixes R5's 2.5x write amplification) + parallel scan.
//   s[k] = sum_e w*dis[d]*g2[s,k] + sum_v dv^2*h[v,k] + N*b2[k]
// ws layout (bytes):
//   [0)            A   : 16M uint2, dst-bucket-sorted, pack=(dst_local<<19)|src
//   [128,000,000)  y   : N f32
//   [130,000,000)  dis : N f32
//   [132,000,000)  g2  : N float2 (dis*hW2)
//   [136,000,000)  meta: counts[NB*NCHK] bases[NB*NCHK] offsets1[NB+1]
//                        rowsum[NB] sacc[2]            (~2.6 MB)
// staging (NB*SPB*BSZ f32 = 32.2 MB) reuses d_in[1] (edge_index, 128 MB):
// src/dst fully consumed after k_scatter1; harness restores d_in every call.
// ---------------------------------------------------------------------------

// per-chunk dst-bucket histogram
__global__ __launch_bounds__(256) void k_count1(const int* __restrict__ dst,
                                                unsigned* __restrict__ counts) {
    __shared__ unsigned hist[NB];
    int c = blockIdx.x;
    for (int t = threadIdx.x; t < NB; t += 256) hist[t] = 0;
    __syncthreads();
    int lo = c * CHK, hi = min(lo + CHK, N_EDGES);
    for (int e = lo + threadIdx.x; e < hi; e += 256)
        atomicAdd(&hist[dst[e] >> BSHIFT], 1u);
    __syncthreads();
    for (int b = threadIdx.x; b < NB; b += 256)
        counts[(size_t)b * NCHK + c] = hist[b];
}

// per-bucket-row exclusive scan over chunks (coalesced), emits row totals
__global__ __launch_bounds__(256) void k_rowscan(const unsigned* __restrict__ counts,
                                                 unsigned* __restrict__ bases,
                                                 unsigned* __restrict__ rowsum) {
    __shared__ unsigned tile[256];
    __shared__ unsigned carry;
    int b = blockIdx.x;
    if (threadIdx.x == 0) carry = 0;
    __syncthreads();
    for (int t0 = 0; t0 < NCHK; t0 += 256) {
        int c = t0 + threadIdx.x;
        unsigned v = (c < NCHK) ? counts[(size_t)b * NCHK + c] : 0u;
        tile[threadIdx.x] = v;
        __syncthreads();
#pragma unroll
        for (int off = 1; off < 256; off <<= 1) {
            unsigned u = (threadIdx.x >= off) ? tile[threadIdx.x - off] : 0u;
            __syncthreads();
            tile[threadIdx.x] += u;
            __syncthreads();
        }
        unsigned excl = tile[threadIdx.x] - v;
        if (c < NCHK) bases[(size_t)b * NCHK + c] = carry + excl;
        __syncthreads();
        if (threadIdx.x == 0) carry += tile[255];
        __syncthreads();
    }
    if (threadIdx.x == 0) rowsum[b] = carry;
}

// exclusive scan over 123 row sums -> bucket offsets
__global__ __launch_bounds__(128) void k_bucketscan(const unsigned* __restrict__ rowsum,
                                                    unsigned* __restrict__ offsets1) {
    __shared__ unsigned tile[128];
    int t = threadIdx.x;
    unsigned v = (t < NB) ? rowsum[t] : 0u;
    tile[t] = v;
    __syncthreads();
#pragma unroll
    for (int off = 1; off < 128; off <<= 1) {
        unsigned u = (t >= off) ? tile[t - off] : 0u;
        __syncthreads();
        tile[t] += u;
        __syncthreads();
    }
    if (t < NB) offsets1[t] = tile[t] - v;
    if (t == 0) offsets1[NB] = tile[127];
}

// LDS chunk-sort scatter: bucket-ordered LDS buffer -> contiguous run writes
__global__ __launch_bounds__(256) void k_scatter1(const int* __restrict__ src,
                                                  const int* __restrict__ dst,
                                                  const float* __restrict__ w,
                                                  const unsigned* __restrict__ bases,
                                                  const unsigned* __restrict__ offsets1,
                                                  uint2* __restrict__ A) {
    __shared__ uint2    buf[CHK];
    __shared__ unsigned hist[NB];
    __shared__ unsigned coff[NB + 1];
    __shared__ unsigned cur[NB];
    __shared__ int      gbase[NB];
    int c = blockIdx.x;
    int lo = c * CHK, hi = min(lo + CHK, N_EDGES);
    int n = hi - lo;
    for (int t = threadIdx.x; t < NB; t += 256) { hist[t] = 0; cur[t] = 0; }
    __syncthreads();
    for (int e = lo + threadIdx.x; e < hi; e += 256)
        atomicAdd(&hist[dst[e] >> BSHIFT], 1u);
    __syncthreads();
    // exclusive scan of hist (NB=123 entries) by thread 0's wave via LDS
    {
        __shared__ unsigned sc[128];
        int t = threadIdx.x;
        if (t < 128) sc[t] = (t < NB) ? hist[t] : 0u;
        __syncthreads();
#pragma unroll
        for (int off = 1; off < 128; off <<= 1) {
            unsigned u = 0;
            if (t < 128 && t >= off) u = sc[t - off];
            __syncthreads();
            if (t < 128) sc[t] += u;
            __syncthreads();
        }
        if (t < NB) coff[t] = sc[t] - hist[t];
        if (t == 0) coff[NB] = (unsigned)n;
        __syncthreads();
        if (t < NB)
            gbase[t] = (int)(offsets1[t] + bases[(size_t)t * NCHK + c]) - (int)coff[t];
    }
    __syncthreads();
    for (int e = lo + threadIdx.x; e < hi; e += 256) {
        int d = dst[e];
        int b = d >> BSHIFT;
        unsigned p = coff[b] + atomicAdd(&cur[b], 1u);
        buf[p] = make_uint2(((unsigned)(d & (BSZ - 1)) << 19) | (unsigned)src[e],
                            __float_as_uint(w[e]));
    }
    __syncthreads();
    // writeout: consecutive LDS slots -> contiguous global runs
    for (int i = threadIdx.x; i < n; i += 256) {
        int blo = 0, bhi = NB;
        while (blo + 1 < bhi) {
            int m = (blo + bhi) >> 1;
            if ((int)coff[m] <= i) blo = m; else bhi = m;
        }
        A[gbase[blo] + i] = buf[i];
    }
}

// slice [e0,e1) of bucket b for this block
__device__ __forceinline__ void slice_bounds(const unsigned* offsets1,
                                             int& b, int& e0, int& e1) {
    b = blockIdx.x >> SPB_SHIFT;
    int s = blockIdx.x & (SPB - 1);
    int base = (int)offsets1[b];
    int len  = (int)offsets1[b + 1] - base;
    e0 = base + (int)(((long long)len * s) >> SPB_SHIFT);
    e1 = base + (int)(((long long)len * (s + 1)) >> SPB_SHIFT);
}

// deg[dl] += w  (LDS bins, coalesced flush to per-block staging slot)
__global__ __launch_bounds__(256) void k_deg(const uint2* __restrict__ A,
                                             const unsigned* __restrict__ offsets1,
                                             float* __restrict__ staging) {
    __shared__ float bins[BSZ];
    for (int i = threadIdx.x; i < BSZ; i += 256) bins[i] = 0.0f;
    int b, e0, e1;
    slice_bounds(offsets1, b, e0, e1);
    __syncthreads();
    for (int e = e0 + threadIdx.x; e < e1; e += 256) {
        uint2 a = A[e];
        atomicAdd(&bins[a.x >> 19], __uint_as_float(a.y));
    }
    __syncthreads();
    float* out = staging + (size_t)blockIdx.x * BSZ;
    for (int i = threadIdx.x; i < BSZ; i += 256) out[i] = bins[i];
}

// fold deg staging -> dis, y
__global__ __launch_bounds__(256) void k_dis(const float* __restrict__ staging,
                                             const float* __restrict__ x,
                                             float* __restrict__ dis,
                                             float* __restrict__ y) {
    int i = blockIdx.x * 256 + threadIdx.x;
    if (i >= N_NODES) return;
    int b = i >> BSHIFT, dl = i & (BSZ - 1);
    const float* st = staging + ((size_t)b << (BSHIFT + SPB_SHIFT)) + dl;
    float deg = 1.0f;  // self-loop
#pragma unroll
    for (int s = 0; s < SPB; ++s) deg += st[(size_t)s << BSHIFT];
    float d = rsqrtf(deg);
    dis[i] = d;
    y[i]   = d * x[i];
}

// inagg[dl] += w * y[src]  (random L2 gather on y; LDS bins; coalesced flush)
__global__ __launch_bounds__(256) void k_in(const uint2* __restrict__ A,
                                            const unsigned* __restrict__ offsets1,
                                            const float* __restrict__ y,
                                            float* __restrict__ staging) {
    __shared__ float bins[BSZ];
    for (int i = threadIdx.x; i < BSZ; i += 256) bins[i] = 0.0f;
    int b, e0, e1;
    slice_bounds(offsets1, b, e0, e1);
    __syncthreads();
    for (int e = e0 + threadIdx.x; e < e1; e += 256) {
        uint2 a = A[e];
        float yv = y[a.x & 0x7FFFFu];
        atomicAdd(&bins[a.x >> 19], __uint_as_float(a.y) * yv);
    }
    __syncthreads();
    float* out = staging + (size_t)blockIdx.x * BSZ;
    for (int i = threadIdx.x; i < BSZ; i += 256) out[i] = bins[i];
}

// fold inagg staging; per-node MLP; g2 = dis*hW2; self-loop term -> sacc
__global__ __launch_bounds__(256) void k_h(const float* __restrict__ staging,
                                           const float* __restrict__ dis,
                                           const float* __restrict__ x,
                                           const float* __restrict__ W1,
                                           const float* __restrict__ b1,
                                           const float* __restrict__ W2,
                                           float2* __restrict__ g2,
                                           float* __restrict__ sacc) {
    int i = blockIdx.x * 256 + threadIdx.x;
    float c0 = 0.0f, c1 = 0.0f;
    if (i < N_NODES) {
        int b = i >> BSHIFT, dl = i & (BSZ - 1);
        const float* st = staging + ((size_t)b << (BSHIFT + SPB_SHIFT)) + dl;
        float inagg = 0.0f;
#pragma unroll
        for (int s = 0; s < SPB; ++s) inagg += st[(size_t)s << BSHIFT];
        float dv   = dis[i];
        float agg1 = dv * (inagg + dv * x[i]);
        float h0 = 0.0f, h1 = 0.0f;
#pragma unroll
        for (int j = 0; j < 16; ++j) {
            float a = fmaxf(fmaf(agg1, W1[j], b1[j]), 0.0f);
            h0 = fmaf(a, W2[2 * j + 0], h0);
            h1 = fmaf(a, W2[2 * j + 1], h1);
        }
        g2[i] = make_float2(dv * h0, dv * h1);
        c0 = dv * dv * h0;
        c1 = dv * dv * h1;
    }
#pragma unroll
    for (int off = 32; off > 0; off >>= 1) {
        c0 += __shfl_down(c0, off, 64);
        c1 += __shfl_down(c1, off, 64);
    }
    __shared__ float red0[4], red1[4];
    int wave = threadIdx.x >> 6, lane = threadIdx.x & 63;
    if (lane == 0) { red0[wave] = c0; red1[wave] = c1; }
    __syncthreads();
    if (threadIdx.x == 0) {
        atomicAdd(&sacc[0], red0[0] + red0[1] + red0[2] + red0[3]);
        atomicAdd(&sacc[1], red1[0] + red1[1] + red1[2] + red1[3]);
    }
}

// pure edge reduction: sum_e w * dis[dst] * g2[src]  (dis LDS-local)
__global__ __launch_bounds__(256) void k_out(const uint2* __restrict__ A,
                                             const unsigned* __restrict__ offsets1,
                                             const float* __restrict__ dis,
                                             const float2* __restrict__ g2,
                                             float* __restrict__ sacc) {
    __shared__ float disL[BSZ];
    int b, e0, e1;
    slice_bounds(offsets1, b, e0, e1);
    int nbase = b << BSHIFT;
    for (int i = threadIdx.x; i < BSZ; i += 256) {
        int node = nbase + i;
        disL[i] = (node < N_NODES) ? dis[node] : 0.0f;
    }
    __syncthreads();
    float c0 = 0.0f, c1 = 0.0f;
    for (int e = e0 + threadIdx.x; e < e1; e += 256) {
        uint2 a = A[e];
        float2 g = g2[a.x & 0x7FFFFu];
        float wd = __uint_as_float(a.y) * disL[a.x >> 19];
        c0 = fmaf(wd, g.x, c0);
        c1 = fmaf(wd, g.y, c1);
    }
#pragma unroll
    for (int off = 32; off > 0; off >>= 1) {
        c0 += __shfl_down(c0, off, 64);
        c1 += __shfl_down(c1, off, 64);
    }
    __shared__ float red0[4], red1[4];
    int wave = threadIdx.x >> 6, lane = threadIdx.x & 63;
    if (lane == 0) { red0[wave] = c0; red1[wave] = c1; }
    __syncthreads();
    if (threadIdx.x == 0) {
        atomicAdd(&sacc[0], red0[0] + red0[1] + red0[2] + red0[3]);
        atomicAdd(&sacc[1], red1[0] + red1[1] + red1[2] + red1[3]);
    }
}

__global__ void k_final(const float* __restrict__ sacc,
                        const float* __restrict__ b2,
                        float* __restrict__ out) {
    if (threadIdx.x == 0 && blockIdx.x == 0) {
        float s0 = sacc[0] + (float)N_NODES * b2[0];
        float s1 = sacc[1] + (float)N_NODES * b2[1];
        float m = fmaxf(s0, s1);
        float e0 = __expf(s0 - m);
        float e1 = __expf(s1 - m);
        float inv = 1.0f / (e0 + e1);
        out[0] = e0 * inv;
        out[1] = e1 * inv;
    }
}

// ---------------- fallback path (R1 structure, ~8 MB ws) ----------------

__global__ __launch_bounds__(256) void k_init_fb(float* __restrict__ deg,
                                                 float* __restrict__ inagg,
                                                 float* __restrict__ outco,
                                                 float* __restrict__ sacc) {
    int i = blockIdx.x * blockDim.x + threadIdx.x;
    if (i < N_NODES) { deg[i] = 1.0f; inagg[i] = 0.0f; outco[i] = 0.0f; }
    if (i < 2) sacc[i] = 0.0f;
}

__global__ __launch_bounds__(256) void k_deg_fb(const int4* __restrict__ dst4,
                                                const float4* __restrict__ w4,
                                                float* __restrict__ deg) {
    int i = blockIdx.x * blockDim.x + threadIdx.x;
    int4 d = dst4[i]; float4 w = w4[i];
    atomicAdd(&deg[d.x], w.x); atomicAdd(&deg[d.y], w.y);
    atomicAdd(&deg[d.z], w.z); atomicAdd(&deg[d.w], w.w);
}

__global__ __launch_bounds__(256) void k_dis_fb(float* __restrict__ degdis,
                                                const float* __restrict__ x,
                                                float* __restrict__ y) {
    int i = blockIdx.x * blockDim.x + threadIdx.x;
    if (i < N_NODES) { float d = rsqrtf(degdis[i]); degdis[i] = d; y[i] = d * x[i]; }
}

__global__ __launch_bounds__(256) void k_edge2_fb(const int4* __restrict__ src4,
                                                  const int4* __restrict__ dst4,
                                                  const float4* __restrict__ w4,
                                                  const float* __restrict__ dis,
                                                  const float* __restrict__ y,
                                                  float* __restrict__ inagg,
                                                  float* __restrict__ outco) {
    int i = blockIdx.x * blockDim.x + threadIdx.x;
    int4 s = src4[i]; int4 d = dst4[i]; float4 w = w4[i];
    atomicAdd(&inagg[d.x], w.x * y[s.x]); atomicAdd(&inagg[d.y], w.y * y[s.y]);
    atomicAdd(&inagg[d.z], w.z * y[s.z]); atomicAdd(&inagg[d.w], w.w * y[s.w]);
    atomicAdd(&outco[s.x], w.x * dis[d.x]); atomicAdd(&outco[s.y], w.y * dis[d.y]);
    atomicAdd(&outco[s.z], w.z * dis[d.z]); atomicAdd(&outco[s.w], w.w * dis[d.w]);
}

__global__ __launch_bounds__(256) void k_node_fb(const float* __restrict__ dis,
                                                 const float* __restrict__ x,
                                                 const float* __restrict__ inagg,
                                                 const float* __restrict__ outco,
                                                 const float* __restrict__ W1,
                                                 const float* __restrict__ b1,
                                                 const float* __restrict__ W2,
                                                 float* __restrict__ sacc) {
    int i = blockIdx.x * blockDim.x + threadIdx.x;
    float c0 = 0.0f, c1 = 0.0f;
    if (i < N_NODES) {
        float dv = dis[i];
        float agg1 = dv * (inagg[i] + dv * x[i]);
        float coef = dv * outco[i] + dv * dv;
        float h0 = 0.0f, h1 = 0.0f;
#pragma unroll
        for (int j = 0; j < 16; ++j) {
            float a = fmaxf(fmaf(agg1, W1[j], b1[j]), 0.0f);
            h0 = fmaf(a, W2[2 * j + 0], h0);
            h1 = fmaf(a, W2[2 * j + 1], h1);
        }
        c0 = coef * h0; c1 = coef * h1;
    }
#pragma unroll
    for (int off = 32; off > 0; off >>= 1) {
        c0 += __shfl_down(c0, off, 64);
        c1 += __shfl_down(c1, off, 64);
    }
    __shared__ float red0[4], red1[4];
    int wave = threadIdx.x >> 6, lane = threadIdx.x & 63;
    if (lane == 0) { red0[wave] = c0; red1[wave] = c1; }
    __syncthreads();
    if (threadIdx.x == 0) {
        atomicAdd(&sacc[0], red0[0] + red0[1] + red0[2] + red0[3]);
        atomicAdd(&sacc[1], red1[0] + red1[1] + red1[2] + red1[3]);
    }
}

extern "C" void kernel_launch(void* const* d_in, const int* in_sizes, int n_in,
                              void* d_out, int out_size, void* d_ws, size_t ws_size,
                              hipStream_t stream) {
    const float* x  = (const float*)d_in[0];
    int*         ei = (int*)d_in[1];            // [2,E] int32 (row0 src, row1 dst)
    const float* ew = (const float*)d_in[2];
    const float* W1 = (const float*)d_in[3];
    const float* b1 = (const float*)d_in[4];
    const float* W2 = (const float*)d_in[5];
    const float* b2 = (const float*)d_in[6];
    float* out = (float*)d_out;

    const int* src = ei;
    const int* dst = ei + N_EDGES;

    const int TB = 256;
    const int nodeBlocks = (N_NODES + TB - 1) / TB;

    // fast-path layout in ws
    char* base = (char*)d_ws;
    uint2*    A   = (uint2*)base;
    float*    y   = (float*)(base + 128000000);
    float*    dis = (float*)(base + 130000000);
    float2*   g2  = (float2*)(base + 132000000);
    unsigned* counts   = (unsigned*)(base + 136000000);
    unsigned* bases    = counts + (size_t)NB * NCHK;
    unsigned* offsets1 = bases + (size_t)NB * NCHK;
    unsigned* rowsum   = offsets1 + (NB + 1);
    float*    sacc     = (float*)(rowsum + NB);
    const size_t fastNeed = (size_t)((char*)(sacc + 2) - base) + 64;

    if (ws_size >= fastNeed) {
        // staging reuses edge_index buffer (consumed after k_scatter1)
        float* staging = (float*)ei;   // NB*SPB*BSZ*4 = 32.2 MB <= 128 MB

        hipMemsetAsync(sacc, 0, 2 * sizeof(float), stream);

        k_count1<<<NCHK, TB, 0, stream>>>(dst, counts);
        k_rowscan<<<NB, TB, 0, stream>>>(counts, bases, rowsum);
        k_bucketscan<<<1, 128, 0, stream>>>(rowsum, offsets1);
        k_scatter1<<<NCHK, TB, 0, stream>>>(src, dst, ew, bases, offsets1, A);
        k_deg<<<NB * SPB, TB, 0, stream>>>(A, offsets1, staging);
        k_dis<<<nodeBlocks, TB, 0, stream>>>(staging, x, dis, y);
        k_in<<<NB * SPB, TB, 0, stream>>>(A, offsets1, y, staging);
        k_h<<<nodeBlocks, TB, 0, stream>>>(staging, dis, x, W1, b1, W2, g2, sacc);
        k_out<<<NB * SPB, TB, 0, stream>>>(A, offsets1, dis, g2, sacc);
        k_final<<<1, 64, 0, stream>>>(sacc, b2, out);
    } else {
        float* ws     = (float*)d_ws;
        float* degdis = ws;
        float* yf     = ws + N_NODES;
        float* inaggf = ws + 2 * N_NODES;
        float* outcof = ws + 3 * N_NODES;
        float* saccf  = ws + 4 * N_NODES;
        const int edgeBlocks = (N_EDGES / 4) / TB;

        k_init_fb<<<nodeBlocks, TB, 0, stream>>>(degdis, inaggf, outcof, saccf);
        k_deg_fb<<<edgeBlocks, TB, 0, stream>>>((const int4*)dst, (const float4*)ew, degdis);
        k_dis_fb<<<nodeBlocks, TB, 0, stream>>>(degdis, x, yf);
        k_edge2_fb<<<edgeBlocks, TB, 0, stream>>>((const int4*)src, (const int4*)dst,
                                                  (const float4*)ew, degdis, yf, inaggf, outcof);
        k_node_fb<<<nodeBlocks, TB, 0, stream>>>(degdis, x, inaggf, outcof, W1, b1, W2, saccf);
        k_final<<<1, 64, 0, stream>>>(saccf, b2, out);
    }
}

// Round 7
// 676.655 us; speedup vs baseline: 4.1182x; 1.1752x over previous
//
#include <hip/hip_runtime.h>
#include <math.h>

constexpr int N_NODES   = 500000;
constexpr int N_EDGES   = 16000000;
constexpr int BSHIFT    = 12;
constexpr int BSZ       = 1 << BSHIFT;                 // 4096 nodes / bucket
constexpr int NB        = (N_NODES + BSZ - 1) / BSZ;   // 123 buckets
constexpr int CHK       = 4096;                        // edges per sort chunk (32 KB LDS buf)
constexpr int NCHK      = (N_EDGES + CHK - 1) / CHK;   // 3907 chunks
constexpr int SPB_SHIFT = 4;
constexpr int SPB       = 1 << SPB_SHIFT;              // 16 consumer slices / bucket

// ---------------------------------------------------------------------------
// v7: like v6 (one-level dst-bucket sort, LDS-binned consumers) but the
// scatter writeout is wave-per-bucket-run (no per-element binary search),
// CHK=4096 for 4 blocks/CU occupancy, and edge reads are int4-vectorized.
//   s[k] = sum_e w*dis[d]*g2[s,k] + sum_v dv^2*h[v,k] + N*b2[k]
// ws layout (bytes):
//   [0)            A   : 16M uint2, dst-bucket-sorted, pack=(dst_local<<19)|src
//   [128,000,000)  y   : N f32
//   [130,000,000)  dis : N f32
//   [132,000,000)  g2  : N float2 (dis*hW2)
//   [136,000,000)  meta: counts[NB*NCHK] bases[NB*NCHK] offsets1[NB+1]
//                        rowsum[NB] sacc[2]            (~3.9 MB)
// staging (NB*SPB*BSZ f32 = 32.2 MB) reuses d_in[1] (edge_index, 128 MB):
// src/dst fully consumed after k_scatter1; harness restores d_in every call.
// ---------------------------------------------------------------------------

// per-chunk dst-bucket histogram (int4 reads; CHK divisible by 4)
__global__ __launch_bounds__(256) void k_count1(const int4* __restrict__ dst4,
                                                unsigned* __restrict__ counts) {
    __shared__ unsigned hist[NB];
    int c = blockIdx.x;
    for (int t = threadIdx.x; t < NB; t += 256) hist[t] = 0;
    __syncthreads();
    int lo4 = c * (CHK / 4);
    int hi4 = min(lo4 + CHK / 4, N_EDGES / 4);
    for (int q = lo4 + threadIdx.x; q < hi4; q += 256) {
        int4 d = dst4[q];
        atomicAdd(&hist[d.x >> BSHIFT], 1u);
        atomicAdd(&hist[d.y >> BSHIFT], 1u);
        atomicAdd(&hist[d.z >> BSHIFT], 1u);
        atomicAdd(&hist[d.w >> BSHIFT], 1u);
    }
    __syncthreads();
    for (int b = threadIdx.x; b < NB; b += 256)
        counts[(size_t)b * NCHK + c] = hist[b];
}

// per-bucket-row exclusive scan over chunks (coalesced), emits row totals
__global__ __launch_bounds__(256) void k_rowscan(const unsigned* __restrict__ counts,
                                                 unsigned* __restrict__ bases,
                                                 unsigned* __restrict__ rowsum) {
    __shared__ unsigned tile[256];
    __shared__ unsigned carry;
    int b = blockIdx.x;
    if (threadIdx.x == 0) carry = 0;
    __syncthreads();
    for (int t0 = 0; t0 < NCHK; t0 += 256) {
        int c = t0 + threadIdx.x;
        unsigned v = (c < NCHK) ? counts[(size_t)b * NCHK + c] : 0u;
        tile[threadIdx.x] = v;
        __syncthreads();
#pragma unroll
        for (int off = 1; off < 256; off <<= 1) {
            unsigned u = (threadIdx.x >= off) ? tile[threadIdx.x - off] : 0u;
            __syncthreads();
            tile[threadIdx.x] += u;
            __syncthreads();
        }
        unsigned excl = tile[threadIdx.x] - v;
        if (c < NCHK) bases[(size_t)b * NCHK + c] = carry + excl;
        __syncthreads();
        if (threadIdx.x == 0) carry += tile[255];
        __syncthreads();
    }
    if (threadIdx.x == 0) rowsum[b] = carry;
}

// exclusive scan over 123 row sums -> bucket offsets
__global__ __launch_bounds__(128) void k_bucketscan(const unsigned* __restrict__ rowsum,
                                                    unsigned* __restrict__ offsets1) {
    __shared__ unsigned tile[128];
    int t = threadIdx.x;
    unsigned v = (t < NB) ? rowsum[t] : 0u;
    tile[t] = v;
    __syncthreads();
#pragma unroll
    for (int off = 1; off < 128; off <<= 1) {
        unsigned u = (t >= off) ? tile[t - off] : 0u;
        __syncthreads();
        tile[t] += u;
        __syncthreads();
    }
    if (t < NB) offsets1[t] = tile[t] - v;
    if (t == 0) offsets1[NB] = tile[127];
}

// LDS chunk-sort scatter; writeout = wave-per-bucket-run (no binary search)
__global__ __launch_bounds__(256) void k_scatter1(const int4* __restrict__ src4,
                                                  const int4* __restrict__ dst4,
                                                  const float4* __restrict__ w4,
                                                  const unsigned* __restrict__ bases,
                                                  const unsigned* __restrict__ offsets1,
                                                  uint2* __restrict__ A) {
    __shared__ uint2    buf[CHK];
    __shared__ unsigned hist[NB];
    __shared__ unsigned coff[NB + 1];
    __shared__ unsigned cur[NB];
    __shared__ int      gbase[NB];
    __shared__ unsigned sc[128];
    int c = blockIdx.x;
    int lo4 = c * (CHK / 4);
    int hi4 = min(lo4 + CHK / 4, N_EDGES / 4);
    int n = (hi4 - lo4) * 4;
    for (int t = threadIdx.x; t < NB; t += 256) { hist[t] = 0; cur[t] = 0; }
    __syncthreads();
    for (int q = lo4 + threadIdx.x; q < hi4; q += 256) {
        int4 d = dst4[q];
        atomicAdd(&hist[d.x >> BSHIFT], 1u);
        atomicAdd(&hist[d.y >> BSHIFT], 1u);
        atomicAdd(&hist[d.z >> BSHIFT], 1u);
        atomicAdd(&hist[d.w >> BSHIFT], 1u);
    }
    __syncthreads();
    {   // exclusive scan of hist (NB entries padded to 128)
        int t = threadIdx.x;
        if (t < 128) sc[t] = (t < NB) ? hist[t] : 0u;
        __syncthreads();
#pragma unroll
        for (int off = 1; off < 128; off <<= 1) {
            unsigned u = 0;
            if (t < 128 && t >= off) u = sc[t - off];
            __syncthreads();
            if (t < 128) sc[t] += u;
            __syncthreads();
        }
        if (t < NB) coff[t] = sc[t] - hist[t];
        if (t == 0) coff[NB] = (unsigned)n;
        __syncthreads();
        if (t < NB)
            gbase[t] = (int)(offsets1[t] + bases[(size_t)t * NCHK + c]) - (int)coff[t];
    }
    __syncthreads();
    for (int q = lo4 + threadIdx.x; q < hi4; q += 256) {
        int4   s = src4[q];
        int4   d = dst4[q];
        float4 w = w4[q];
        {
            int b = d.x >> BSHIFT;
            unsigned p = coff[b] + atomicAdd(&cur[b], 1u);
            buf[p] = make_uint2(((unsigned)(d.x & (BSZ - 1)) << 19) | (unsigned)s.x,
                                __float_as_uint(w.x));
        }
        {
            int b = d.y >> BSHIFT;
            unsigned p = coff[b] + atomicAdd(&cur[b], 1u);
            buf[p] = make_uint2(((unsigned)(d.y & (BSZ - 1)) << 19) | (unsigned)s.y,
                                __float_as_uint(w.y));
        }
        {
            int b = d.z >> BSHIFT;
            unsigned p = coff[b] + atomicAdd(&cur[b], 1u);
            buf[p] = make_uint2(((unsigned)(d.z & (BSZ - 1)) << 19) | (unsigned)s.z,
                                __float_as_uint(w.z));
        }
        {
            int b = d.w >> BSHIFT;
            unsigned p = coff[b] + atomicAdd(&cur[b], 1u);
            buf[p] = make_uint2(((unsigned)(d.w & (BSZ - 1)) << 19) | (unsigned)s.w,
                                __float_as_uint(w.w));
        }
    }
    __syncthreads();
    // writeout: wave w takes buckets w, w+4, ... ; each run is contiguous
    int wave = threadIdx.x >> 6;
    int lane = threadIdx.x & 63;
    for (int b = wave; b < NB; b += 4) {
        int r0 = (int)coff[b], r1 = (int)coff[b + 1];
        int gb = gbase[b];
        for (int i = r0 + lane; i < r1; i += 64)
            A[gb + i] = buf[i];
    }
}

// slice [e0,e1) of bucket b for this block
__device__ __forceinline__ void slice_bounds(const unsigned* offsets1,
                                             int& b, int& e0, int& e1) {
    b = blockIdx.x >> SPB_SHIFT;
    int s = blockIdx.x & (SPB - 1);
    int base = (int)offsets1[b];
    int len  = (int)offsets1[b + 1] - base;
    e0 = base + (int)(((long long)len * s) >> SPB_SHIFT);
    e1 = base + (int)(((long long)len * (s + 1)) >> SPB_SHIFT);
}

// deg[dl] += w  (LDS bins, coalesced flush to per-block staging slot)
__global__ __launch_bounds__(256) void k_deg(const uint2* __restrict__ A,
                                             const unsigned* __restrict__ offsets1,
                                             float* __restrict__ staging) {
    __shared__ float bins[BSZ];
    for (int i = threadIdx.x; i < BSZ; i += 256) bins[i] = 0.0f;
    int b, e0, e1;
    slice_bounds(offsets1, b, e0, e1);
    __syncthreads();
    for (int e = e0 + threadIdx.x; e < e1; e += 256) {
        uint2 a = A[e];
        atomicAdd(&bins[a.x >> 19], __uint_as_float(a.y));
    }
    __syncthreads();
    float* out = staging + (size_t)blockIdx.x * BSZ;
    for (int i = threadIdx.x; i < BSZ; i += 256) out[i] = bins[i];
}

// fold deg staging -> dis, y
__global__ __launch_bounds__(256) void k_dis(const float* __restrict__ staging,
                                             const float* __restrict__ x,
                                             float* __restrict__ dis,
                                             float* __restrict__ y) {
    int i = blockIdx.x * 256 + threadIdx.x;
    if (i >= N_NODES) return;
    int b = i >> BSHIFT, dl = i & (BSZ - 1);
    const float* st = staging + ((size_t)b << (BSHIFT + SPB_SHIFT)) + dl;
    float deg = 1.0f;  // self-loop
#pragma unroll
    for (int s = 0; s < SPB; ++s) deg += st[(size_t)s << BSHIFT];
    float d = rsqrtf(deg);
    dis[i] = d;
    y[i]   = d * x[i];
}

// inagg[dl] += w * y[src]  (random L2 gather on y; LDS bins; coalesced flush)
__global__ __launch_bounds__(256) void k_in(const uint2* __restrict__ A,
                                            const unsigned* __restrict__ offsets1,
                                            const float* __restrict__ y,
                                            float* __restrict__ staging) {
    __shared__ float bins[BSZ];
    for (int i = threadIdx.x; i < BSZ; i += 256) bins[i] = 0.0f;
    int b, e0, e1;
    slice_bounds(offsets1, b, e0, e1);
    __syncthreads();
    for (int e = e0 + threadIdx.x; e < e1; e += 256) {
        uint2 a = A[e];
        float yv = y[a.x & 0x7FFFFu];
        atomicAdd(&bins[a.x >> 19], __uint_as_float(a.y) * yv);
    }
    __syncthreads();
    float* out = staging + (size_t)blockIdx.x * BSZ;
    for (int i = threadIdx.x; i < BSZ; i += 256) out[i] = bins[i];
}

// fold inagg staging; per-node MLP; g2 = dis*hW2; self-loop term -> sacc
__global__ __launch_bounds__(256) void k_h(const float* __restrict__ staging,
                                           const float* __restrict__ dis,
                                           const float* __restrict__ x,
                                           const float* __restrict__ W1,
                                           const float* __restrict__ b1,
                                           const float* __restrict__ W2,
                                           float2* __restrict__ g2,
                                           float* __restrict__ sacc) {
    int i = blockIdx.x * 256 + threadIdx.x;
    float c0 = 0.0f, c1 = 0.0f;
    if (i < N_NODES) {
        int b = i >> BSHIFT, dl = i & (BSZ - 1);
        const float* st = staging + ((size_t)b << (BSHIFT + SPB_SHIFT)) + dl;
        float inagg = 0.0f;
#pragma unroll
        for (int s = 0; s < SPB; ++s) inagg += st[(size_t)s << BSHIFT];
        float dv   = dis[i];
        float agg1 = dv * (inagg + dv * x[i]);
        float h0 = 0.0f, h1 = 0.0f;
#pragma unroll
        for (int j = 0; j < 16; ++j) {
            float a = fmaxf(fmaf(agg1, W1[j], b1[j]), 0.0f);
            h0 = fmaf(a, W2[2 * j + 0], h0);
            h1 = fmaf(a, W2[2 * j + 1], h1);
        }
        g2[i] = make_float2(dv * h0, dv * h1);
        c0 = dv * dv * h0;
        c1 = dv * dv * h1;
    }
#pragma unroll
    for (int off = 32; off > 0; off >>= 1) {
        c0 += __shfl_down(c0, off, 64);
        c1 += __shfl_down(c1, off, 64);
    }
    __shared__ float red0[4], red1[4];
    int wave = threadIdx.x >> 6, lane = threadIdx.x & 63;
    if (lane == 0) { red0[wave] = c0; red1[wave] = c1; }
    __syncthreads();
    if (threadIdx.x == 0) {
        atomicAdd(&sacc[0], red0[0] + red0[1] + red0[2] + red0[3]);
        atomicAdd(&sacc[1], red1[0] + red1[1] + red1[2] + red1[3]);
    }
}

// pure edge reduction: sum_e w * dis[dst] * g2[src]  (dis LDS-local)
__global__ __launch_bounds__(256) void k_out(const uint2* __restrict__ A,
                                             const unsigned* __restrict__ offsets1,
                                             const float* __restrict__ dis,
                                             const float2* __restrict__ g2,
                                             float* __restrict__ sacc) {
    __shared__ float disL[BSZ];
    int b, e0, e1;
    slice_bounds(offsets1, b, e0, e1);
    int nbase = b << BSHIFT;
    for (int i = threadIdx.x; i < BSZ; i += 256) {
        int node = nbase + i;
        disL[i] = (node < N_NODES) ? dis[node] : 0.0f;
    }
    __syncthreads();
    float c0 = 0.0f, c1 = 0.0f;
    for (int e = e0 + threadIdx.x; e < e1; e += 256) {
        uint2 a = A[e];
        float2 g = g2[a.x & 0x7FFFFu];
        float wd = __uint_as_float(a.y) * disL[a.x >> 19];
        c0 = fmaf(wd, g.x, c0);
        c1 = fmaf(wd, g.y, c1);
    }
#pragma unroll
    for (int off = 32; off > 0; off >>= 1) {
        c0 += __shfl_down(c0, off, 64);
        c1 += __shfl_down(c1, off, 64);
    }
    __shared__ float red0[4], red1[4];
    int wave = threadIdx.x >> 6, lane = threadIdx.x & 63;
    if (lane == 0) { red0[wave] = c0; red1[wave] = c1; }
    __syncthreads();
    if (threadIdx.x == 0) {
        atomicAdd(&sacc[0], red0[0] + red0[1] + red0[2] + red0[3]);
        atomicAdd(&sacc[1], red1[0] + red1[1] + red1[2] + red1[3]);
    }
}

__global__ void k_final(const float* __restrict__ sacc,
                        const float* __restrict__ b2,
                        float* __restrict__ out) {
    if (threadIdx.x == 0 && blockIdx.x == 0) {
        float s0 = sacc[0] + (float)N_NODES * b2[0];
        float s1 = sacc[1] + (float)N_NODES * b2[1];
        float m = fmaxf(s0, s1);
        float e0 = __expf(s0 - m);
        float e1 = __expf(s1 - m);
        float inv = 1.0f / (e0 + e1);
        out[0] = e0 * inv;
        out[1] = e1 * inv;
    }
}

// ---------------- fallback path (R1 structure, ~8 MB ws) ----------------

__global__ __launch_bounds__(256) void k_init_fb(float* __restrict__ deg,
                                                 float* __restrict__ inagg,
                                                 float* __restrict__ outco,
                                                 float* __restrict__ sacc) {
    int i = blockIdx.x * blockDim.x + threadIdx.x;
    if (i < N_NODES) { deg[i] = 1.0f; inagg[i] = 0.0f; outco[i] = 0.0f; }
    if (i < 2) sacc[i] = 0.0f;
}

__global__ __launch_bounds__(256) void k_deg_fb(const int4* __restrict__ dst4,
                                                const float4* __restrict__ w4,
                                                float* __restrict__ deg) {
    int i = blockIdx.x * blockDim.x + threadIdx.x;
    int4 d = dst4[i]; float4 w = w4[i];
    atomicAdd(&deg[d.x], w.x); atomicAdd(&deg[d.y], w.y);
    atomicAdd(&deg[d.z], w.z); atomicAdd(&deg[d.w], w.w);
}

__global__ __launch_bounds__(256) void k_dis_fb(float* __restrict__ degdis,
                                                const float* __restrict__ x,
                                                float* __restrict__ y) {
    int i = blockIdx.x * blockDim.x + threadIdx.x;
    if (i < N_NODES) { float d = rsqrtf(degdis[i]); degdis[i] = d; y[i] = d * x[i]; }
}

__global__ __launch_bounds__(256) void k_edge2_fb(const int4* __restrict__ src4,
                                                  const int4* __restrict__ dst4,
                                                  const float4* __restrict__ w4,
                                                  const float* __restrict__ dis,
                                                  const float* __restrict__ y,
                                                  float* __restrict__ inagg,
                                                  float* __restrict__ outco) {
    int i = blockIdx.x * blockDim.x + threadIdx.x;
    int4 s = src4[i]; int4 d = dst4[i]; float4 w = w4[i];
    atomicAdd(&inagg[d.x], w.x * y[s.x]); atomicAdd(&inagg[d.y], w.y * y[s.y]);
    atomicAdd(&inagg[d.z], w.z * y[s.z]); atomicAdd(&inagg[d.w], w.w * y[s.w]);
    atomicAdd(&outco[s.x], w.x * dis[d.x]); atomicAdd(&outco[s.y], w.y * dis[d.y]);
    atomicAdd(&outco[s.z], w.z * dis[d.z]); atomicAdd(&outco[s.w], w.w * dis[d.w]);
}

__global__ __launch_bounds__(256) void k_node_fb(const float* __restrict__ dis,
                                                 const float* __restrict__ x,
                                                 const float* __restrict__ inagg,
                                                 const float* __restrict__ outco,
                                                 const float* __restrict__ W1,
                                                 const float* __restrict__ b1,
                                                 const float* __restrict__ W2,
                                                 float* __restrict__ sacc) {
    int i = blockIdx.x * blockDim.x + threadIdx.x;
    float c0 = 0.0f, c1 = 0.0f;
    if (i < N_NODES) {
        float dv = dis[i];
        float agg1 = dv * (inagg[i] + dv * x[i]);
        float coef = dv * outco[i] + dv * dv;
        float h0 = 0.0f, h1 = 0.0f;
#pragma unroll
        for (int j = 0; j < 16; ++j) {
            float a = fmaxf(fmaf(agg1, W1[j], b1[j]), 0.0f);
            h0 = fmaf(a, W2[2 * j + 0], h0);
            h1 = fmaf(a, W2[2 * j + 1], h1);
        }
        c0 = coef * h0; c1 = coef * h1;
    }
#pragma unroll
    for (int off = 32; off > 0; off >>= 1) {
        c0 += __shfl_down(c0, off, 64);
        c1 += __shfl_down(c1, off, 64);
    }
    __shared__ float red0[4], red1[4];
    int wave = threadIdx.x >> 6, lane = threadIdx.x & 63;
    if (lane == 0) { red0[wave] = c0; red1[wave] = c1; }
    __syncthreads();
    if (threadIdx.x == 0) {
        atomicAdd(&sacc[0], red0[0] + red0[1] + red0[2] + red0[3]);
        atomicAdd(&sacc[1], red1[0] + red1[1] + red1[2] + red1[3]);
    }
}

extern "C" void kernel_launch(void* const* d_in, const int* in_sizes, int n_in,
                              void* d_out, int out_size, void* d_ws, size_t ws_size,
                              hipStream_t stream) {
    const float* x  = (const float*)d_in[0];
    int*         ei = (int*)d_in[1];            // [2,E] int32 (row0 src, row1 dst)
    const float* ew = (const float*)d_in[2];
    const float* W1 = (const float*)d_in[3];
    const float* b1 = (const float*)d_in[4];
    const float* W2 = (const float*)d_in[5];
    const float* b2 = (const float*)d_in[6];
    float* out = (float*)d_out;

    const int* src = ei;
    const int* dst = ei + N_EDGES;

    const int TB = 256;
    const int nodeBlocks = (N_NODES + TB - 1) / TB;

    // fast-path layout in ws
    char* base = (char*)d_ws;
    uint2*    A   = (uint2*)base;
    float*    y   = (float*)(base + 128000000);
    float*    dis = (float*)(base + 130000000);
    float2*   g2  = (float2*)(base + 132000000);
    unsigned* counts   = (unsigned*)(base + 136000000);
    unsigned* bases    = counts + (size_t)NB * NCHK;
    unsigned* offsets1 = bases + (size_t)NB * NCHK;
    unsigned* rowsum   = offsets1 + (NB + 1);
    float*    sacc     = (float*)(rowsum + NB);
    const size_t fastNeed = (size_t)((char*)(sacc + 2) - base) + 64;

    if (ws_size >= fastNeed) {
        // staging reuses edge_index buffer (consumed after k_scatter1)
        float* staging = (float*)ei;   // NB*SPB*BSZ*4 = 32.2 MB <= 128 MB

        hipMemsetAsync(sacc, 0, 2 * sizeof(float), stream);

        k_count1<<<NCHK, TB, 0, stream>>>((const int4*)dst, counts);
        k_rowscan<<<NB, TB, 0, stream>>>(counts, bases, rowsum);
        k_bucketscan<<<1, 128, 0, stream>>>(rowsum, offsets1);
        k_scatter1<<<NCHK, TB, 0, stream>>>((const int4*)src, (const int4*)dst,
                                            (const float4*)ew, bases, offsets1, A);
        k_deg<<<NB * SPB, TB, 0, stream>>>(A, offsets1, staging);
        k_dis<<<nodeBlocks, TB, 0, stream>>>(staging, x, dis, y);
        k_in<<<NB * SPB, TB, 0, stream>>>(A, offsets1, y, staging);
        k_h<<<nodeBlocks, TB, 0, stream>>>(staging, dis, x, W1, b1, W2, g2, sacc);
        k_out<<<NB * SPB, TB, 0, stream>>>(A, offsets1, dis, g2, sacc);
        k_final<<<1, 64, 0, stream>>>(sacc, b2, out);
    } else {
        float* ws     = (float*)d_ws;
        float* degdis = ws;
        float* yf     = ws + N_NODES;
        float* inaggf = ws + 2 * N_NODES;
        float* outcof = ws + 3 * N_NODES;
        float* saccf  = ws + 4 * N_NODES;
        const int edgeBlocks = (N_EDGES / 4) / TB;

        k_init_fb<<<nodeBlocks, TB, 0, stream>>>(degdis, inaggf, outcof, saccf);
        k_deg_fb<<<edgeBlocks, TB, 0, stream>>>((const int4*)dst, (const float4*)ew, degdis);
        k_dis_fb<<<nodeBlocks, TB, 0, stream>>>(degdis, x, yf);
        k_edge2_fb<<<edgeBlocks, TB, 0, stream>>>((const int4*)src, (const int4*)dst,
                                                  (const float4*)ew, degdis, yf, inaggf, outcof);
        k_node_fb<<<nodeBlocks, TB, 0, stream>>>(degdis, x, inaggf, outcof, W1, b1, W2, saccf);
        k_final<<<1, 64, 0, stream>>>(saccf, b2, out);
    }
}